// Round 13
// baseline (235.926 us; speedup 1.0000x reference)
//
#include <hip/hip_runtime.h>
#include <hip/hip_bf16.h>
#include <hip/hip_fp16.h>
#include <math.h>

// Problem: h = z @ W + b  (z [N,256] fp32, W [256,256] fp32, b [256])
//          out[e] = sigmoid(dot(h[src[e]], h[dst[e]]))  for E edges
// N = 100000, E = 300000, D = 256.
//
// R13: R12 + depth-2 A-prefetch. At iter kb, raw A(kb+1) and A(kb+2) are
// both in flight (slot parity via unroll 2, no rotation movs) -> each
// HBM A-load gets ~2 kb-phases to complete instead of 1. Costs +16 VGPR
// (raw loads only; unlike R6's failed B-dbuf which burned 64 regs on
// L2-hot data). fp16 single-term MFMA (absmax 0.0117 vs 0.02 threshold).
// BM=128, 512 thr, 8 waves x 32x128 strips; 16KB B double-buffer staged
// via global_load_lds, 1 barrier/kb. h fp16.

#define D_DIM 256
#define BM 128

typedef __attribute__((ext_vector_type(8))) _Float16 half8;
typedef __attribute__((ext_vector_type(4))) float f32x4;

__device__ half8 g_Wf[8 * 256 * 4];   // [kb][n][qd] -> 16B fp16 frag, 128 KB

// 8192 threads: t -> (kb, qd, n), n fastest => coalesced row reads of W.
__global__ __launch_bounds__(256) void pack_w_kernel(const float* __restrict__ W) {
  int t = blockIdx.x * 256 + threadIdx.x;   // 0..8191
  int kb = t >> 10;
  int qd = (t >> 8) & 3;
  int n  = t & 255;
  half8 o;
#pragma unroll
  for (int j = 0; j < 8; j++)
    o[j] = (_Float16)W[(size_t)(kb * 32 + qd * 8 + j) * D_DIM + n];
  g_Wf[(kb * 256 + n) * 4 + qd] = o;
}

// Stage one kb's 16 KB of B frags into an LDS buffer; 8 waves x 2 KB.
__device__ inline void stage_b(int kb, char* buf, int wv, int lane) {
  const char* gsrc = (const char*)g_Wf + (size_t)kb * 16384 + wv * 2048;
  char* ldst = buf + wv * 2048;
#pragma unroll
  for (int i = 0; i < 2; i++) {
    __builtin_amdgcn_global_load_lds(
        (const __attribute__((address_space(1))) void*)(gsrc + i * 1024 + lane * 16),
        (__attribute__((address_space(3))) void*)(ldst + i * 1024),
        16, 0, 0);
  }
}

__global__ __launch_bounds__(512) void gemm_mfma_kernel(
    const float* __restrict__ z, const float* __restrict__ b,
    __half* __restrict__ h, int nrows) {
  // 2x16KB B double-buffer; epilogue tiles (8x4352B=34816B) alias the lot.
  __shared__ char smem[34816];
  const int tid = threadIdx.x;
  const int lane = tid & 63;
  const int wv = tid >> 6;          // 0..7
  const int mg = wv >> 1;           // m-group: rows mg*32 .. +31 (2 frags)
  const int nh = wv & 1;            // n-half: cols nh*128 .. +127
  const int fr = lane & 15;
  const int qd = lane >> 4;
  const int row0 = blockIdx.x * BM + mg * 32;

  f32x4 acc[2][8];
#pragma unroll
  for (int i = 0; i < 2; i++)
#pragma unroll
    for (int j = 0; j < 8; j++) acc[i][j] = (f32x4)0.f;

  const float* zrow[2];
#pragma unroll
  for (int fm = 0; fm < 2; fm++) {
    int r = row0 + fm * 16 + fr;
    r = r < nrows ? r : (nrows - 1);
    zrow[fm] = z + (size_t)r * D_DIM + qd * 8;
  }

  // Two A slots (parity): slot p holds raw A for the next kb with kb&1==p.
  // preload kb=0 -> slot0, kb=1 -> slot1; B kb=0 -> LDS buf0.
  float4 a0[2][2], a1[2][2];   // [slot][fm]
#pragma unroll
  for (int s = 0; s < 2; s++)
#pragma unroll
    for (int fm = 0; fm < 2; fm++) {
      const float* p = zrow[fm] + s * 32;
      a0[s][fm] = *(const float4*)(p);
      a1[s][fm] = *(const float4*)(p + 4);
    }
  stage_b(0, smem, wv, lane);
  __syncthreads();

#pragma unroll 2
  for (int kb = 0; kb < 8; kb++) {
    const int sl = kb & 1;
    char* cur = smem + sl * 16384;
    // stage kb+1 into the other buffer; latency spans the whole MFMA block
    if (kb < 7) stage_b(kb + 1, smem + ((kb + 1) & 1) * 16384, wv, lane);

    // convert current A fp32 -> fp16 frags (16 v_cvt)
    half8 af[2];
#pragma unroll
    for (int fm = 0; fm < 2; fm++) {
      af[fm][0] = (_Float16)a0[sl][fm].x; af[fm][1] = (_Float16)a0[sl][fm].y;
      af[fm][2] = (_Float16)a0[sl][fm].z; af[fm][3] = (_Float16)a0[sl][fm].w;
      af[fm][4] = (_Float16)a1[sl][fm].x; af[fm][5] = (_Float16)a1[sl][fm].y;
      af[fm][6] = (_Float16)a1[sl][fm].z; af[fm][7] = (_Float16)a1[sl][fm].w;
    }
    // depth-2 prefetch: refill this slot with kb+2's raw A (2 phases away)
    if (kb < 6) {
#pragma unroll
      for (int fm = 0; fm < 2; fm++) {
        const float* p = zrow[fm] + (kb + 2) * 32;
        a0[sl][fm] = *(const float4*)(p);
        a1[sl][fm] = *(const float4*)(p + 4);
      }
    }

    const half8* buf = (const half8*)cur;
#pragma unroll
    for (int fn = 0; fn < 8; fn++) {
      int fi = (nh * 128 + fn * 16 + fr) * 4 + qd;   // contiguous 1KB/wave
      half8 bf = buf[fi];
#pragma unroll
      for (int fm = 0; fm < 2; fm++)
        acc[fm][fn] = __builtin_amdgcn_mfma_f32_16x16x32_f16(af[fm], bf, acc[fm][fn], 0, 0, 0);
    }
    // one barrier/kb: drains kb+1 staging AND fences cur reads before
    // kb+1's stage_b(kb+2) overwrites cur.
    __syncthreads();
  }

  // Epilogue: per-wave 16x136-half LDS tile (272B stride: 2-way max, free),
  // reused for both m-frags (same-wave LDS ordering; verified R4-R12).
  __half* et = (__half*)(smem + wv * 4352);
  float bias[8];
#pragma unroll
  for (int fn = 0; fn < 8; fn++) bias[fn] = b[nh * 128 + fn * 16 + fr];

#pragma unroll
  for (int fm = 0; fm < 2; fm++) {
#pragma unroll
    for (int fn = 0; fn < 8; fn++)
#pragma unroll
      for (int r = 0; r < 4; r++)
        et[(qd * 4 + r) * 136 + fn * 16 + fr] = __float2half(acc[fm][fn][r] + bias[fn]);
#pragma unroll
    for (int p = 0; p < 4; p++) {
      int idx = p * 64 + lane;        // 0..255
      int rr = idx >> 4;              // 0..15
      int cc = idx & 15;              // 16B chunk within 256B row-half
      float4 v = *(const float4*)(et + rr * 136 + cc * 8);
      int row = row0 + fm * 16 + rr;
      if (row < nrows)
        *(float4*)(h + (size_t)row * D_DIM + nh * 128 + cc * 8) = v;
    }
  }
}

// 1 wave per 8 edges; per edge ONE 1KB load instr: lanes 0-31 cover the
// 512B src row, lanes 32-63 the dst row. Pair via shfl_xor(32), butterfly.
__global__ __launch_bounds__(256) void edge_dot_kernel(
    const int* __restrict__ ei, const __half* __restrict__ h,
    float* __restrict__ out, int E) {
  int wid = (blockIdx.x * blockDim.x + threadIdx.x) >> 6;
  int lane = threadIdx.x & 63;
  int ebase = wid * 8;
  if (ebase >= E) return;
  const int half = lane >> 5;      // 0=src row, 1=dst row
  const int off = lane & 31;       // float4 chunk within the 512B row

  float4 v[8];
#pragma unroll
  for (int q = 0; q < 8; q++) {
    int e = ebase + q;
    e = e < E ? e : (E - 1);
    int node = half ? ei[E + e] : ei[e];   // uniform per 32-lane half
    v[q] = *(const float4*)((const __half*)h + (size_t)node * D_DIM + off * 8);
  }

  float res = 0.f;
#pragma unroll
  for (int q = 0; q < 8; q++) {
    float4 w;
    w.x = __shfl_xor(v[q].x, 32);
    w.y = __shfl_xor(v[q].y, 32);
    w.z = __shfl_xor(v[q].z, 32);
    w.w = __shfl_xor(v[q].w, 32);
    const __half2* a2 = (const __half2*)&v[q];
    const __half2* b2 = (const __half2*)&w;
    float part = 0.f;
#pragma unroll
    for (int j = 0; j < 4; j++) {
      float2 fa = __half22float2(a2[j]);
      float2 fb = __half22float2(b2[j]);
      part += fa.x * fb.x + fa.y * fb.y;
    }
#pragma unroll
    for (int m = 1; m <= 16; m <<= 1) part += __shfl_xor(part, m);
    res = (lane == q) ? part : res;    // lanes 0..7 collect the 8 results
  }
  if (lane < 8) {
    int e = ebase + lane;
    if (e < E) out[e] = 1.0f / (1.0f + __expf(-res));
  }
}

extern "C" void kernel_launch(void* const* d_in, const int* in_sizes, int n_in,
                              void* d_out, int out_size, void* d_ws, size_t ws_size,
                              hipStream_t stream) {
  const float* z  = (const float*)d_in[0];
  const int*   ei = (const int*)d_in[1];
  const float* W  = (const float*)d_in[2];
  const float* b  = (const float*)d_in[3];
  float* out = (float*)d_out;
  __half* h  = (__half*)d_ws;   // 100000*256*2 = 51.2 MB scratch

  const int nnodes = in_sizes[0] / D_DIM;
  const int E = in_sizes[1] / 2;

  pack_w_kernel<<<32, 256, 0, stream>>>(W);

  dim3 grid_gemm((nnodes + BM - 1) / BM);
  gemm_mfma_kernel<<<grid_gemm, 512, 0, stream>>>(z, b, h, nnodes);

  int waves = (E + 7) / 8;                        // 1 wave per 8 edges
  dim3 grid_edge(((size_t)waves * 64 + 255) / 256);
  edge_dot_kernel<<<grid_edge, 256, 0, stream>>>(ei, h, out, E);
}

// Round 14
// 220.922 us; speedup vs baseline: 1.0679x; 1.0679x over previous
//
#include <hip/hip_runtime.h>
#include <hip/hip_bf16.h>
#include <hip/hip_fp16.h>
#include <math.h>

// Problem: h = z @ W + b  (z [N,256] fp32, W [256,256] fp32, b [256])
//          out[e] = sigmoid(dot(h[src[e]], h[dst[e]]))  for E edges
// N = 100000, E = 300000, D = 256.
//
// R14: barrier-free K-loop via LDS-persistent W. R12/R13 proved the per-kb
// __syncthreads (vmcnt(0) drain) is the structural ceiling (~60 us): any
// register-funded prefetch just loses occupancy (R6, R13). Now: W-fp16
// (128 KB) staged in two 64 KB halves; each wave owns 16 rows x 256 cols
// (zero A redundancy, acc[16]=64 AGPR); ALL 16 A float4 loads issued
// upfront (fly during half-0 staging, drained by the stage barrier we pay
// anyway). K-loop = cvt + ds_read_b128 + MFMA only — no barriers, no
// globals. 4 barriers per block total. Expect HBM-bound ~25-35 us.
// fp16 single-term MFMA (absmax 0.0117 vs 0.02). h fp16.

#define D_DIM 256
#define BM 128

typedef __attribute__((ext_vector_type(8))) _Float16 half8;
typedef __attribute__((ext_vector_type(4))) float f32x4;

__device__ half8 g_Wf[8 * 256 * 4];   // [kb][n][qd] -> 16B fp16 frag, 128 KB

// 8192 threads: t -> (kb, qd, n), n fastest => coalesced row reads of W.
__global__ __launch_bounds__(256) void pack_w_kernel(const float* __restrict__ W) {
  int t = blockIdx.x * 256 + threadIdx.x;   // 0..8191
  int kb = t >> 10;
  int qd = (t >> 8) & 3;
  int n  = t & 255;
  half8 o;
#pragma unroll
  for (int j = 0; j < 8; j++)
    o[j] = (_Float16)W[(size_t)(kb * 32 + qd * 8 + j) * D_DIM + n];
  g_Wf[(kb * 256 + n) * 4 + qd] = o;
}

// Stage a 64 KB half of packed W into LDS; 8 waves x 8 KB (8 x 1KB calls).
__device__ inline void stage_half(const char* gsrc, char* buf, int wv, int lane) {
  const char* s = gsrc + wv * 8192;
  char* d = buf + wv * 8192;
#pragma unroll
  for (int i = 0; i < 8; i++) {
    __builtin_amdgcn_global_load_lds(
        (const __attribute__((address_space(1))) void*)(s + i * 1024 + lane * 16),
        (__attribute__((address_space(3))) void*)(d + i * 1024),
        16, 0, 0);
  }
}

__global__ __launch_bounds__(512) void gemm_mfma_kernel(
    const float* __restrict__ z, const float* __restrict__ b,
    __half* __restrict__ h, int nrows) {
  __shared__ char smem[65536];      // one W half (kb group of 4); epi aliases
  const int tid = threadIdx.x;
  const int lane = tid & 63;
  const int wv = tid >> 6;          // 0..7: wave owns rows wv*16..+15, all cols
  const int fr = lane & 15;
  const int qd = lane >> 4;
  const int row0 = blockIdx.x * BM + wv * 16;

  int r = row0 + fr;
  r = r < nrows ? r : (nrows - 1);
  const float* zrow = z + (size_t)r * D_DIM + qd * 8;

  // Issue ALL A loads upfront: 8 kb x 32B/lane. In flight during staging;
  // drained by the first stage barrier (which we pay regardless).
  float4 a0[8], a1[8];
#pragma unroll
  for (int kb = 0; kb < 8; kb++) {
    const float* p = zrow + kb * 32;
    a0[kb] = *(const float4*)(p);
    a1[kb] = *(const float4*)(p + 4);
  }

  f32x4 acc[16];
#pragma unroll
  for (int j = 0; j < 16; j++) acc[j] = (f32x4)0.f;

  // ---- half 0: kb 0..3 ----
  stage_half((const char*)g_Wf, smem, wv, lane);
  __syncthreads();                  // stage + A drained
#pragma unroll
  for (int s = 0; s < 4; s++) {
    half8 af;
    af[0] = (_Float16)a0[s].x; af[1] = (_Float16)a0[s].y;
    af[2] = (_Float16)a0[s].z; af[3] = (_Float16)a0[s].w;
    af[4] = (_Float16)a1[s].x; af[5] = (_Float16)a1[s].y;
    af[6] = (_Float16)a1[s].z; af[7] = (_Float16)a1[s].w;
#pragma unroll
    for (int fn = 0; fn < 16; fn++) {
      // byte addr: s*16384 + fn*1024 + fr*64 + qd*16 (contiguous 1KB/fn)
      half8 bf = *(const half8*)(smem + s * 16384 + fn * 1024 + fr * 64 + qd * 16);
      acc[fn] = __builtin_amdgcn_mfma_f32_16x16x32_f16(af, bf, acc[fn], 0, 0, 0);
    }
  }
  __syncthreads();                  // all waves done reading half 0

  // ---- half 1: kb 4..7 ----
  stage_half((const char*)g_Wf + 65536, smem, wv, lane);
  __syncthreads();                  // staged
#pragma unroll
  for (int s = 0; s < 4; s++) {
    half8 af;
    af[0] = (_Float16)a0[s + 4].x; af[1] = (_Float16)a0[s + 4].y;
    af[2] = (_Float16)a0[s + 4].z; af[3] = (_Float16)a0[s + 4].w;
    af[4] = (_Float16)a1[s + 4].x; af[5] = (_Float16)a1[s + 4].y;
    af[6] = (_Float16)a1[s + 4].z; af[7] = (_Float16)a1[s + 4].w;
#pragma unroll
    for (int fn = 0; fn < 16; fn++) {
      half8 bf = *(const half8*)(smem + s * 16384 + fn * 1024 + fr * 64 + qd * 16);
      acc[fn] = __builtin_amdgcn_mfma_f32_16x16x32_f16(af, bf, acc[fn], 0, 0, 0);
    }
  }
  __syncthreads();                  // W buffer -> epilogue tile reuse

  // Epilogue: per-wave 16x136-half LDS tile (272B stride: 2-way max, free),
  // two 128-col phases (same-wave LDS ordering; verified R4-R13).
  __half* et = (__half*)(smem + wv * 4352);
#pragma unroll
  for (int ph = 0; ph < 2; ph++) {
#pragma unroll
    for (int f8 = 0; f8 < 8; f8++) {
      int fn = ph * 8 + f8;
      float bias = b[fn * 16 + fr];
#pragma unroll
      for (int rr = 0; rr < 4; rr++)
        et[(qd * 4 + rr) * 136 + f8 * 16 + fr] = __float2half(acc[fn][rr] + bias);
    }
#pragma unroll
    for (int p = 0; p < 4; p++) {
      int idx = p * 64 + lane;        // 0..255
      int rr = idx >> 4;              // 0..15
      int cc = idx & 15;              // 16B chunk within 256B row-half
      float4 v = *(const float4*)(et + rr * 136 + cc * 8);
      int row = row0 + rr;
      if (row < nrows)
        *(float4*)(h + (size_t)row * D_DIM + ph * 128 + cc * 8) = v;
    }
  }
}

// 1 wave per 8 edges; per edge ONE 1KB load instr: lanes 0-31 cover the
// 512B src row, lanes 32-63 the dst row. Pair via shfl_xor(32), butterfly.
__global__ __launch_bounds__(256) void edge_dot_kernel(
    const int* __restrict__ ei, const __half* __restrict__ h,
    float* __restrict__ out, int E) {
  int wid = (blockIdx.x * blockDim.x + threadIdx.x) >> 6;
  int lane = threadIdx.x & 63;
  int ebase = wid * 8;
  if (ebase >= E) return;
  const int half = lane >> 5;      // 0=src row, 1=dst row
  const int off = lane & 31;       // float4 chunk within the 512B row

  float4 v[8];
#pragma unroll
  for (int q = 0; q < 8; q++) {
    int e = ebase + q;
    e = e < E ? e : (E - 1);
    int node = half ? ei[E + e] : ei[e];   // uniform per 32-lane half
    v[q] = *(const float4*)((const __half*)h + (size_t)node * D_DIM + off * 8);
  }

  float res = 0.f;
#pragma unroll
  for (int q = 0; q < 8; q++) {
    float4 w;
    w.x = __shfl_xor(v[q].x, 32);
    w.y = __shfl_xor(v[q].y, 32);
    w.z = __shfl_xor(v[q].z, 32);
    w.w = __shfl_xor(v[q].w, 32);
    const __half2* a2 = (const __half2*)&v[q];
    const __half2* b2 = (const __half2*)&w;
    float part = 0.f;
#pragma unroll
    for (int j = 0; j < 4; j++) {
      float2 fa = __half22float2(a2[j]);
      float2 fb = __half22float2(b2[j]);
      part += fa.x * fb.x + fa.y * fb.y;
    }
#pragma unroll
    for (int m = 1; m <= 16; m <<= 1) part += __shfl_xor(part, m);
    res = (lane == q) ? part : res;    // lanes 0..7 collect the 8 results
  }
  if (lane < 8) {
    int e = ebase + lane;
    if (e < E) out[e] = 1.0f / (1.0f + __expf(-res));
  }
}

extern "C" void kernel_launch(void* const* d_in, const int* in_sizes, int n_in,
                              void* d_out, int out_size, void* d_ws, size_t ws_size,
                              hipStream_t stream) {
  const float* z  = (const float*)d_in[0];
  const int*   ei = (const int*)d_in[1];
  const float* W  = (const float*)d_in[2];
  const float* b  = (const float*)d_in[3];
  float* out = (float*)d_out;
  __half* h  = (__half*)d_ws;   // 100000*256*2 = 51.2 MB scratch

  const int nnodes = in_sizes[0] / D_DIM;
  const int E = in_sizes[1] / 2;

  pack_w_kernel<<<32, 256, 0, stream>>>(W);

  dim3 grid_gemm((nnodes + BM - 1) / BM);
  gemm_mfma_kernel<<<grid_gemm, 512, 0, stream>>>(z, b, h, nnodes);

  int waves = (E + 7) / 8;                        // 1 wave per 8 edges
  dim3 grid_edge(((size_t)waves * 64 + 255) / 256);
  edge_dot_kernel<<<grid_edge, 256, 0, stream>>>(ei, h, out, E);
}